// Round 1
// 818.662 us; speedup vs baseline: 1.0884x; 1.0884x over previous
//
#include <hip/hip_runtime.h>

// SoftAggONNX on MI355X (gfx950)
// N=131072 elements, C=512 channels, G=4096 groups.
// Pipeline:
//  K0a: x fp32 -> bf16 (ws.xb)
//  K0b: Wf,Wg,Wh fp32 [K x C] -> bf16 transposed [C x K] (ws.wft/wgt/wht)
//  K2a-d: counting sort of ix -> per-group row lists (atomic-free reduce later)
//  K1:  dual GEMM fx = x@Wf (+bf), eg = exp(x@Wg+bg); bf16 MFMA 16x16x32,
//       128x128x32 tiles, global_load_lds(16B), XOR-swizzled LDS (2-way only),
//       XCD-aware block swizzle for A-tile L2 reuse. fx/eg -> two halves of d_out.
//       K-loop: DOUBLE-BUFFERED LDS, prefetch tile kt+1 before computing kt,
//       one barrier per k-step (T3-minimum pipeline).
//  K3:  per-group one-pass reduce: y[g,c] = (sum fx*eg)/(sum eg)  -> ws.ybf (bf16)
//  K4:  z = y@Wh + bh (same GEMM template, fp32 out) -> ws.z
//  K5:  out[i,:] = z[ix[i],:]   (overwrites all of d_out)

#define NN 131072
#define CC 512
#define GG 4096

typedef unsigned short ushortT;
typedef unsigned int uintT;
typedef __attribute__((ext_vector_type(8))) short short8;
typedef __attribute__((ext_vector_type(4))) float f32x4;

__device__ __forceinline__ ushortT f2bf(float f) {
  uintT u = __float_as_uint(f);
  u += 0x7FFFu + ((u >> 16) & 1u);   // round-to-nearest-even
  return (ushortT)(u >> 16);
}
__device__ __forceinline__ float bf2f(uintT u) {
  return __uint_as_float(u << 16);
}

__device__ __forceinline__ void gl_lds16(const void* gsrc, void* ldst) {
  __builtin_amdgcn_global_load_lds(
      (const __attribute__((address_space(1))) void*)gsrc,
      (__attribute__((address_space(3))) void*)ldst,
      16, 0, 0);
}

// ---------------- K0a: x -> bf16 ----------------
__global__ __launch_bounds__(256) void convert_x(const float* __restrict__ x,
                                                 ushortT* __restrict__ xb) {
  size_t i = ((size_t)blockIdx.x * 256 + threadIdx.x) * 8;
  f32x4 u = *(const f32x4*)&x[i];
  f32x4 v = *(const f32x4*)&x[i + 4];
  short8 r;
  r[0] = (short)f2bf(u[0]); r[1] = (short)f2bf(u[1]);
  r[2] = (short)f2bf(u[2]); r[3] = (short)f2bf(u[3]);
  r[4] = (short)f2bf(v[0]); r[5] = (short)f2bf(v[1]);
  r[6] = (short)f2bf(v[2]); r[7] = (short)f2bf(v[3]);
  *(short8*)&xb[i] = r;
}

// ---------------- K0b: W [K x C] -> Wt bf16 [C x K] ----------------
__global__ __launch_bounds__(256) void transpose_w(
    const float* __restrict__ Wf, const float* __restrict__ Wg,
    const float* __restrict__ Wh, ushortT* __restrict__ wft,
    ushortT* __restrict__ wgt, ushortT* __restrict__ wht) {
  const float* W = (blockIdx.z == 0) ? Wf : ((blockIdx.z == 1) ? Wg : Wh);
  ushortT* O = (blockIdx.z == 0) ? wft : ((blockIdx.z == 1) ? wgt : wht);
  __shared__ float tile[32][33];
  int tx = threadIdx.x, ty = threadIdx.y;  // 32 x 8
  int kb = blockIdx.y * 32, cb = blockIdx.x * 32;
#pragma unroll
  for (int s = 0; s < 32; s += 8)
    tile[ty + s][tx] = W[(size_t)(kb + ty + s) * CC + cb + tx];
  __syncthreads();
#pragma unroll
  for (int s = 0; s < 32; s += 8)
    O[(size_t)(cb + ty + s) * CC + kb + tx] = f2bf(tile[tx][ty + s]);
}

// ---------------- K2: counting sort of ix ----------------
__global__ __launch_bounds__(256) void zero_cnt(int* __restrict__ cnt) {
  cnt[blockIdx.x * 256 + threadIdx.x] = 0;
}
__global__ __launch_bounds__(256) void hist_ix(const int* __restrict__ ix,
                                               int* __restrict__ cnt) {
  int i = blockIdx.x * 256 + threadIdx.x;
  atomicAdd(&cnt[ix[i]], 1);
}
__global__ __launch_bounds__(256) void scan_cnt(const int* __restrict__ cnt,
                                                int* __restrict__ offs,
                                                int* __restrict__ cur) {
  __shared__ int partial[256];
  int t = threadIdx.x;
  int base = t * 16;
  int local[16];
  int s = 0;
#pragma unroll
  for (int i = 0; i < 16; ++i) { local[i] = s; s += cnt[base + i]; }
  partial[t] = s;
  __syncthreads();
  if (t == 0) {
    int acc = 0;
    for (int i = 0; i < 256; ++i) { int v = partial[i]; partial[i] = acc; acc += v; }
  }
  __syncthreads();
  int p = partial[t];
#pragma unroll
  for (int i = 0; i < 16; ++i) {
    int o = p + local[i];
    offs[base + i] = o;
    cur[base + i] = o;
  }
  if (t == 255) offs[GG] = p + s;  // == N
}
__global__ __launch_bounds__(256) void fill_rows(const int* __restrict__ ix,
                                                 int* __restrict__ cur,
                                                 int* __restrict__ rows) {
  int i = blockIdx.x * 256 + threadIdx.x;
  int p = atomicAdd(&cur[ix[i]], 1);
  rows[p] = i;
}

// ---------------- GEMM (MODE 0: dual fx/exp bf16-out; MODE 1: z fp32-out) ---
// A [M x 512] bf16 row-major; B = Wt [512(c) x 512(k)] bf16 row-major.
// Tile 128x128x32, 256 threads (4 waves), mfma_f32_16x16x32_bf16.
// LDS tiles [128 rows x 32 k] bf16, 16B granules XOR-swizzled:
//   granule g of row r stored at slot g ^ ((r>>1)&3)  -> 2-way-only bank alias.
// Double-buffered: buffer b at ushort offset b*8192; A [0,4096) B [4096,8192).
template <int MODE>
__global__ __launch_bounds__(256) void gemm_bf16(
    const ushortT* __restrict__ A, const ushortT* __restrict__ B0,
    const ushortT* __restrict__ B1, const float* __restrict__ bias0,
    const float* __restrict__ bias1, ushortT* __restrict__ out0,
    ushortT* __restrict__ out1, float* __restrict__ outf) {
  __shared__ ushortT lds[16384];  // 32 KB, two 16 KB buffers
  int mtile, nblk;
  if (MODE == 0) {
    // XCD swizzle: 8 sibling n-blocks of one m-tile land on the same XCD.
    int id = blockIdx.x;
    int xcd = id & 7;
    int j = id >> 3;
    mtile = xcd * 128 + (j >> 3);
    nblk = j & 7;
  } else {
    nblk = blockIdx.x;
    mtile = blockIdx.y;
  }
  const int m0 = mtile * 128;
  const int n0 = (MODE == 0 ? (nblk & 3) : nblk) * 128;
  const ushortT* Bt = (MODE == 0 && nblk >= 4) ? B1 : B0;

  const int t = threadIdx.x;
  const int w = t >> 6;
  const int lane = t & 63;
  const int rl = lane & 15, q = lane >> 4;

  // staging: per wave 2 instrs x 1KB for each of A,B
  const char* pA[2];
  const char* pB[2];
#pragma unroll
  for (int j = 0; j < 2; ++j) {
    int o = (w * 2 + j) * 1024 + lane * 16;   // linear LDS byte pos
    int row = o >> 6;                          // 64B per row
    int slot = (o >> 4) & 3;
    int gran = slot ^ ((row >> 1) & 3);        // which global granule lands here
    pA[j] = (const char*)A + (size_t)(m0 + row) * 1024 + gran * 16;
    pB[j] = (const char*)Bt + (size_t)(n0 + row) * 1024 + gran * 16;
  }

  // frag read offsets (ushort units): byte addr = r*64 + (q^((r>>1)&3))*16
  int aoff[2], boff[8];
#pragma unroll
  for (int mt = 0; mt < 2; ++mt) {
    int r = w * 32 + mt * 16 + rl;
    aoff[mt] = r * 32 + ((q ^ ((r >> 1) & 3)) * 8);
  }
#pragma unroll
  for (int nt = 0; nt < 8; ++nt) {
    int r = nt * 16 + rl;
    boff[nt] = r * 32 + ((q ^ ((r >> 1) & 3)) * 8);
  }

  f32x4 acc[2][8];
#pragma unroll
  for (int a = 0; a < 2; ++a)
#pragma unroll
    for (int b = 0; b < 8; ++b) acc[a][b] = (f32x4){0.f, 0.f, 0.f, 0.f};

  // prologue: stage kt=0 into buffer 0
  {
    ushortT* dA = &lds[(w * 2) * 512];
    ushortT* dB = &lds[4096 + (w * 2) * 512];
    gl_lds16(pA[0], dA);
    gl_lds16(pA[1], dA + 512);
    gl_lds16(pB[0], dB);
    gl_lds16(pB[1], dB + 512);
  }
  __syncthreads();

  int cur = 0;
#pragma unroll
  for (int kt = 0; kt < 16; ++kt) {
    const int nxt = cur ^ 1;
    // issue next-tile staging first so its latency overlaps this tile's compute
    if (kt < 15) {
      const int kof = (kt + 1) * 64;  // 32 k * 2B
      ushortT* dA = &lds[nxt * 8192 + (w * 2) * 512];
      ushortT* dB = &lds[nxt * 8192 + 4096 + (w * 2) * 512];
      gl_lds16(pA[0] + kof, dA);
      gl_lds16(pA[1] + kof, dA + 512);
      gl_lds16(pB[0] + kof, dB);
      gl_lds16(pB[1] + kof, dB + 512);
    }
    const ushortT* ldsAc = &lds[cur * 8192];
    const ushortT* ldsBc = &lds[cur * 8192 + 4096];
    short8 av0 = *(const short8*)&ldsAc[aoff[0]];
    short8 av1 = *(const short8*)&ldsAc[aoff[1]];
    short8 bv[8];
#pragma unroll
    for (int nt = 0; nt < 8; ++nt) bv[nt] = *(const short8*)&ldsBc[boff[nt]];
#pragma unroll
    for (int nt = 0; nt < 8; ++nt) {
      acc[0][nt] = __builtin_amdgcn_mfma_f32_16x16x32_bf16(av0, bv[nt], acc[0][nt], 0, 0, 0);
      acc[1][nt] = __builtin_amdgcn_mfma_f32_16x16x32_bf16(av1, bv[nt], acc[1][nt], 0, 0, 0);
    }
    // one barrier per k-step: drains this iteration's prefetch (issued a full
    // compute-phase ago) and guarantees all waves finished reading buf[cur].
    __syncthreads();
    cur = nxt;
  }

  // epilogue: C/D layout col = lane&15, row = (lane>>4)*4 + reg
  const float* bias = (MODE == 0) ? (nblk >= 4 ? bias1 : bias0) : bias0;
  float bcol[8];
#pragma unroll
  for (int nt = 0; nt < 8; ++nt) bcol[nt] = bias[n0 + nt * 16 + rl];
  const int row0 = m0 + w * 32 + q * 4;
#pragma unroll
  for (int mt = 0; mt < 2; ++mt) {
#pragma unroll
    for (int nt = 0; nt < 8; ++nt) {
      f32x4 v = acc[mt][nt];
      int col = n0 + nt * 16 + rl;
#pragma unroll
      for (int r = 0; r < 4; ++r) {
        int row = row0 + mt * 16 + r;
        float val = v[r] + bcol[nt];
        if (MODE == 0) {
          if (nblk < 4)
            out0[(size_t)row * CC + col] = f2bf(val);
          else
            out1[(size_t)row * CC + col] = f2bf(__expf(val));
        } else {
          outf[(size_t)row * CC + col] = val;
        }
      }
    }
  }
}

// ---------------- K3: per-group one-pass reduce ----------------
// y[g,c] = (sum_i fx*eg) / (sum_i eg); thread handles 2 channels.
__global__ __launch_bounds__(256) void group_reduce(
    const ushortT* __restrict__ expb, const ushortT* __restrict__ fxb,
    const int* __restrict__ offs, const int* __restrict__ rows,
    ushortT* __restrict__ ybf) {
  int g = blockIdx.x;
  int t = threadIdx.x;
  int c0 = t * 2;
  int beg = offs[g], end = offs[g + 1];
  float se0 = 0.f, se1 = 0.f, sf0 = 0.f, sf1 = 0.f;
  for (int j = beg; j < end; ++j) {
    int r = rows[j];
    uintT e = *(const uintT*)&expb[(size_t)r * CC + c0];
    uintT f = *(const uintT*)&fxb[(size_t)r * CC + c0];
    float e0 = bf2f(e & 0xffffu), e1 = bf2f(e >> 16);
    float f0 = bf2f(f & 0xffffu), f1 = bf2f(f >> 16);
    se0 += e0; se1 += e1;
    sf0 += f0 * e0; sf1 += f1 * e1;
  }
  float y0 = (se0 != 0.f) ? sf0 / se0 : 0.f;
  float y1 = (se1 != 0.f) ? sf1 / se1 : 0.f;
  uintT pk = ((uintT)f2bf(y1) << 16) | (uintT)f2bf(y0);
  *(uintT*)&ybf[(size_t)g * CC + c0] = pk;
}

// ---------------- K5: gather ----------------
__global__ __launch_bounds__(256) void gather_out(const int* __restrict__ ix,
                                                  const float* __restrict__ z,
                                                  float* __restrict__ out) {
  size_t tid = (size_t)blockIdx.x * 256 + threadIdx.x;  // N*128 threads
  int i = (int)(tid >> 7);
  int c4 = ((int)tid & 127) << 2;
  int g = ix[i];
  f32x4 v = *(const f32x4*)&z[(size_t)g * CC + c4];
  *(f32x4*)&out[(size_t)i * CC + c4] = v;
}

extern "C" void kernel_launch(void* const* d_in, const int* in_sizes, int n_in,
                              void* d_out, int out_size, void* d_ws,
                              size_t ws_size, hipStream_t stream) {
  (void)in_sizes; (void)n_in; (void)out_size; (void)ws_size;
  const float* x = (const float*)d_in[0];
  const int* ix = (const int*)d_in[1];
  const float* Wf = (const float*)d_in[2];
  const float* bf_ = (const float*)d_in[3];
  const float* Wg = (const float*)d_in[4];
  const float* bg = (const float*)d_in[5];
  const float* Wh = (const float*)d_in[6];
  const float* bh = (const float*)d_in[7];

  char* ws = (char*)d_ws;
  size_t off = 0;
  ushortT* xb = (ushortT*)(ws + off); off += (size_t)NN * CC * 2;       // 128 MB
  ushortT* wft = (ushortT*)(ws + off); off += (size_t)CC * CC * 2;
  ushortT* wgt = (ushortT*)(ws + off); off += (size_t)CC * CC * 2;
  ushortT* wht = (ushortT*)(ws + off); off += (size_t)CC * CC * 2;
  ushortT* ybf = (ushortT*)(ws + off); off += (size_t)GG * CC * 2;      // 4 MB
  float* z = (float*)(ws + off); off += (size_t)GG * CC * 4;            // 8 MB
  int* cnt = (int*)(ws + off); off += (size_t)GG * 4;
  int* offs = (int*)(ws + off); off += (size_t)(GG + 64) * 4;
  int* cur = (int*)(ws + off); off += (size_t)GG * 4;
  int* rows = (int*)(ws + off); off += (size_t)NN * 4;

  // fx (bf16) and exp_gx (bf16) live in the two halves of d_out until K5.
  ushortT* fxb = (ushortT*)d_out;
  ushortT* expb = (ushortT*)d_out + (size_t)NN * CC;
  float* out = (float*)d_out;

  convert_x<<<dim3(32768), dim3(256), 0, stream>>>(x, xb);
  transpose_w<<<dim3(16, 16, 3), dim3(32, 8), 0, stream>>>(Wf, Wg, Wh, wft, wgt, wht);
  zero_cnt<<<dim3(16), dim3(256), 0, stream>>>(cnt);
  hist_ix<<<dim3(512), dim3(256), 0, stream>>>(ix, cnt);
  scan_cnt<<<dim3(1), dim3(256), 0, stream>>>(cnt, offs, cur);
  fill_rows<<<dim3(512), dim3(256), 0, stream>>>(ix, cur, rows);
  gemm_bf16<0><<<dim3(8192), dim3(256), 0, stream>>>(xb, wft, wgt, bf_, bg, fxb, expb, nullptr);
  group_reduce<<<dim3(GG), dim3(256), 0, stream>>>(expb, fxb, offs, rows, ybf);
  gemm_bf16<1><<<dim3(4, 32), dim3(256), 0, stream>>>(ybf, wht, nullptr, bh, nullptr, nullptr, nullptr, z);
  gather_out<<<dim3(65536), dim3(256), 0, stream>>>(ix, z, out);
}

// Round 2
// 809.313 us; speedup vs baseline: 1.1010x; 1.0116x over previous
//
#include <hip/hip_runtime.h>

// SoftAggONNX on MI355X (gfx950)
// N=131072 elements, C=512 channels, G=4096 groups.
// Pipeline:
//  K0a: x fp32 -> bf16 (ws.xb)
//  K0b: Wf,Wg,Wh fp32 [K x C] -> bf16 transposed [C x K] (ws.wft/wgt/wht)
//  K2a-d: counting sort of ix -> per-group row lists (atomic-free reduce later)
//  K1:  dual GEMM fx = x@Wf (+bf), eg = exp(x@Wg+bg); bf16 MFMA 16x16x32,
//       128x128x32 tiles, global_load_lds(16B), XOR-swizzled LDS (2-way only),
//       XCD-aware block swizzle for A-tile L2 reuse. fx/eg -> two halves of d_out.
//       K-loop: 3-buffer LDS, prefetch distance 2, raw s_barrier + counted
//       s_waitcnt vmcnt(4) -- loads stay in flight ACROSS barriers (T4).
//  K3:  per-group one-pass reduce: y[g,c] = (sum fx*eg)/(sum eg)  -> ws.ybf (bf16)
//  K4:  z = y@Wh + bh (same GEMM template, fp32 out) -> ws.z
//  K5:  out[i,:] = z[ix[i],:]   (overwrites all of d_out)

#define NN 131072
#define CC 512
#define GG 4096

typedef unsigned short ushortT;
typedef unsigned int uintT;
typedef __attribute__((ext_vector_type(8))) short short8;
typedef __attribute__((ext_vector_type(4))) float f32x4;

#define WAITV4 asm volatile("s_waitcnt vmcnt(4)" ::: "memory")
#define WAITV0 asm volatile("s_waitcnt vmcnt(0)" ::: "memory")

__device__ __forceinline__ ushortT f2bf(float f) {
  uintT u = __float_as_uint(f);
  u += 0x7FFFu + ((u >> 16) & 1u);   // round-to-nearest-even
  return (ushortT)(u >> 16);
}
__device__ __forceinline__ float bf2f(uintT u) {
  return __uint_as_float(u << 16);
}

__device__ __forceinline__ void gl_lds16(const void* gsrc, void* ldst) {
  __builtin_amdgcn_global_load_lds(
      (const __attribute__((address_space(1))) void*)gsrc,
      (__attribute__((address_space(3))) void*)ldst,
      16, 0, 0);
}

// ---------------- K0a: x -> bf16 ----------------
__global__ __launch_bounds__(256) void convert_x(const float* __restrict__ x,
                                                 ushortT* __restrict__ xb) {
  size_t i = ((size_t)blockIdx.x * 256 + threadIdx.x) * 8;
  f32x4 u = *(const f32x4*)&x[i];
  f32x4 v = *(const f32x4*)&x[i + 4];
  short8 r;
  r[0] = (short)f2bf(u[0]); r[1] = (short)f2bf(u[1]);
  r[2] = (short)f2bf(u[2]); r[3] = (short)f2bf(u[3]);
  r[4] = (short)f2bf(v[0]); r[5] = (short)f2bf(v[1]);
  r[6] = (short)f2bf(v[2]); r[7] = (short)f2bf(v[3]);
  *(short8*)&xb[i] = r;
}

// ---------------- K0b: W [K x C] -> Wt bf16 [C x K] ----------------
__global__ __launch_bounds__(256) void transpose_w(
    const float* __restrict__ Wf, const float* __restrict__ Wg,
    const float* __restrict__ Wh, ushortT* __restrict__ wft,
    ushortT* __restrict__ wgt, ushortT* __restrict__ wht) {
  const float* W = (blockIdx.z == 0) ? Wf : ((blockIdx.z == 1) ? Wg : Wh);
  ushortT* O = (blockIdx.z == 0) ? wft : ((blockIdx.z == 1) ? wgt : wht);
  __shared__ float tile[32][33];
  int tx = threadIdx.x, ty = threadIdx.y;  // 32 x 8
  int kb = blockIdx.y * 32, cb = blockIdx.x * 32;
#pragma unroll
  for (int s = 0; s < 32; s += 8)
    tile[ty + s][tx] = W[(size_t)(kb + ty + s) * CC + cb + tx];
  __syncthreads();
#pragma unroll
  for (int s = 0; s < 32; s += 8)
    O[(size_t)(cb + ty + s) * CC + kb + tx] = f2bf(tile[tx][ty + s]);
}

// ---------------- K2: counting sort of ix ----------------
__global__ __launch_bounds__(256) void zero_cnt(int* __restrict__ cnt) {
  cnt[blockIdx.x * 256 + threadIdx.x] = 0;
}
__global__ __launch_bounds__(256) void hist_ix(const int* __restrict__ ix,
                                               int* __restrict__ cnt) {
  int i = blockIdx.x * 256 + threadIdx.x;
  atomicAdd(&cnt[ix[i]], 1);
}
__global__ __launch_bounds__(256) void scan_cnt(const int* __restrict__ cnt,
                                                int* __restrict__ offs,
                                                int* __restrict__ cur) {
  __shared__ int partial[256];
  int t = threadIdx.x;
  int base = t * 16;
  int local[16];
  int s = 0;
#pragma unroll
  for (int i = 0; i < 16; ++i) { local[i] = s; s += cnt[base + i]; }
  partial[t] = s;
  __syncthreads();
  if (t == 0) {
    int acc = 0;
    for (int i = 0; i < 256; ++i) { int v = partial[i]; partial[i] = acc; acc += v; }
  }
  __syncthreads();
  int p = partial[t];
#pragma unroll
  for (int i = 0; i < 16; ++i) {
    int o = p + local[i];
    offs[base + i] = o;
    cur[base + i] = o;
  }
  if (t == 255) offs[GG] = p + s;  // == N
}
__global__ __launch_bounds__(256) void fill_rows(const int* __restrict__ ix,
                                                 int* __restrict__ cur,
                                                 int* __restrict__ rows) {
  int i = blockIdx.x * 256 + threadIdx.x;
  int p = atomicAdd(&cur[ix[i]], 1);
  rows[p] = i;
}

// ---------------- GEMM (MODE 0: dual fx/exp bf16-out; MODE 1: z fp32-out) ---
// A [M x 512] bf16 row-major; B = Wt [512(c) x 512(k)] bf16 row-major.
// Tile 128x128x32, 256 threads (4 waves), mfma_f32_16x16x32_bf16.
// LDS tiles [128 rows x 32 k] bf16, 16B granules XOR-swizzled:
//   granule g of row r stored at slot g ^ ((r>>1)&3)  -> 2-way-only bank alias.
// K-loop: 3 buffers (ushort offset b*8192; A [0,4096) B [4096,8192)),
// prefetch distance 2, one raw s_barrier + counted vmcnt per k-step.
template <int MODE>
__global__ __launch_bounds__(256) void gemm_bf16(
    const ushortT* __restrict__ A, const ushortT* __restrict__ B0,
    const ushortT* __restrict__ B1, const float* __restrict__ bias0,
    const float* __restrict__ bias1, ushortT* __restrict__ out0,
    ushortT* __restrict__ out1, float* __restrict__ outf) {
  __shared__ ushortT lds[24576];  // 48 KB, three 16 KB buffers
  int mtile, nblk;
  if (MODE == 0) {
    // XCD swizzle: 8 sibling n-blocks of one m-tile land on the same XCD.
    int id = blockIdx.x;
    int xcd = id & 7;
    int j = id >> 3;
    mtile = xcd * 128 + (j >> 3);
    nblk = j & 7;
  } else {
    nblk = blockIdx.x;
    mtile = blockIdx.y;
  }
  const int m0 = mtile * 128;
  const int n0 = (MODE == 0 ? (nblk & 3) : nblk) * 128;
  const ushortT* Bt = (MODE == 0 && nblk >= 4) ? B1 : B0;

  const int t = threadIdx.x;
  const int w = t >> 6;
  const int lane = t & 63;
  const int rl = lane & 15, q = lane >> 4;

  // staging: per wave 2 instrs x 1KB for each of A,B
  const char* pA[2];
  const char* pB[2];
#pragma unroll
  for (int j = 0; j < 2; ++j) {
    int o = (w * 2 + j) * 1024 + lane * 16;   // linear LDS byte pos
    int row = o >> 6;                          // 64B per row
    int slot = (o >> 4) & 3;
    int gran = slot ^ ((row >> 1) & 3);        // which global granule lands here
    pA[j] = (const char*)A + (size_t)(m0 + row) * 1024 + gran * 16;
    pB[j] = (const char*)Bt + (size_t)(n0 + row) * 1024 + gran * 16;
  }

  // frag read offsets (ushort units): byte addr = r*64 + (q^((r>>1)&3))*16
  int aoff[2], boff[8];
#pragma unroll
  for (int mt = 0; mt < 2; ++mt) {
    int r = w * 32 + mt * 16 + rl;
    aoff[mt] = r * 32 + ((q ^ ((r >> 1) & 3)) * 8);
  }
#pragma unroll
  for (int nt = 0; nt < 8; ++nt) {
    int r = nt * 16 + rl;
    boff[nt] = r * 32 + ((q ^ ((r >> 1) & 3)) * 8);
  }

  f32x4 acc[2][8];
#pragma unroll
  for (int a = 0; a < 2; ++a)
#pragma unroll
    for (int b = 0; b < 8; ++b) acc[a][b] = (f32x4){0.f, 0.f, 0.f, 0.f};

  // prologue: stage tile 0 -> buf0, tile 1 -> buf1 (8 loads in flight/wave)
#pragma unroll
  for (int tt = 0; tt < 2; ++tt) {
    ushortT* dA = &lds[tt * 8192 + (w * 2) * 512];
    ushortT* dB = &lds[tt * 8192 + 4096 + (w * 2) * 512];
    const int kof = tt * 64;
    gl_lds16(pA[0] + kof, dA);
    gl_lds16(pA[1] + kof, dA + 512);
    gl_lds16(pB[0] + kof, dB);
    gl_lds16(pB[1] + kof, dB + 512);
  }

#pragma unroll
  for (int kt = 0; kt < 16; ++kt) {
    // my tile-kt loads landed (tile kt+1's 4 stay in flight across the barrier)
    if (kt == 15) { WAITV0; } else { WAITV4; }
    __builtin_amdgcn_s_barrier();   // now ALL waves' tile-kt loads landed
    asm volatile("" ::: "memory");  // compiler fence: no LDS-read hoisting
    if (kt < 14) {
      // overwrite the buffer read at kt-1 (all waves finished it: they passed
      // this barrier only after consuming their kt-1 fragments)
      const int tt = kt + 2;
      ushortT* dA = &lds[(tt % 3) * 8192 + (w * 2) * 512];
      ushortT* dB = &lds[(tt % 3) * 8192 + 4096 + (w * 2) * 512];
      const int kof = tt * 64;
      gl_lds16(pA[0] + kof, dA);
      gl_lds16(pA[1] + kof, dA + 512);
      gl_lds16(pB[0] + kof, dB);
      gl_lds16(pB[1] + kof, dB + 512);
    }
    const ushortT* ldsAc = &lds[(kt % 3) * 8192];
    const ushortT* ldsBc = ldsAc + 4096;
    short8 av0 = *(const short8*)&ldsAc[aoff[0]];
    short8 av1 = *(const short8*)&ldsAc[aoff[1]];
    short8 bv[8];
#pragma unroll
    for (int nt = 0; nt < 8; ++nt) bv[nt] = *(const short8*)&ldsBc[boff[nt]];
#pragma unroll
    for (int nt = 0; nt < 8; ++nt) {
      acc[0][nt] = __builtin_amdgcn_mfma_f32_16x16x32_bf16(av0, bv[nt], acc[0][nt], 0, 0, 0);
      acc[1][nt] = __builtin_amdgcn_mfma_f32_16x16x32_bf16(av1, bv[nt], acc[1][nt], 0, 0, 0);
    }
  }

  // epilogue: C/D layout col = lane&15, row = (lane>>4)*4 + reg
  const float* bias = (MODE == 0) ? (nblk >= 4 ? bias1 : bias0) : bias0;
  float bcol[8];
#pragma unroll
  for (int nt = 0; nt < 8; ++nt) bcol[nt] = bias[n0 + nt * 16 + rl];
  const int row0 = m0 + w * 32 + q * 4;
#pragma unroll
  for (int mt = 0; mt < 2; ++mt) {
#pragma unroll
    for (int nt = 0; nt < 8; ++nt) {
      f32x4 v = acc[mt][nt];
      int col = n0 + nt * 16 + rl;
#pragma unroll
      for (int r = 0; r < 4; ++r) {
        int row = row0 + mt * 16 + r;
        float val = v[r] + bcol[nt];
        if (MODE == 0) {
          if (nblk < 4)
            out0[(size_t)row * CC + col] = f2bf(val);
          else
            out1[(size_t)row * CC + col] = f2bf(__expf(val));
        } else {
          outf[(size_t)row * CC + col] = val;
        }
      }
    }
  }
}

// ---------------- K3: per-group one-pass reduce ----------------
// y[g,c] = (sum_i fx*eg) / (sum_i eg); thread handles 2 channels.
__global__ __launch_bounds__(256) void group_reduce(
    const ushortT* __restrict__ expb, const ushortT* __restrict__ fxb,
    const int* __restrict__ offs, const int* __restrict__ rows,
    ushortT* __restrict__ ybf) {
  int g = blockIdx.x;
  int t = threadIdx.x;
  int c0 = t * 2;
  int beg = offs[g], end = offs[g + 1];
  float se0 = 0.f, se1 = 0.f, sf0 = 0.f, sf1 = 0.f;
  for (int j = beg; j < end; ++j) {
    int r = rows[j];
    uintT e = *(const uintT*)&expb[(size_t)r * CC + c0];
    uintT f = *(const uintT*)&fxb[(size_t)r * CC + c0];
    float e0 = bf2f(e & 0xffffu), e1 = bf2f(e >> 16);
    float f0 = bf2f(f & 0xffffu), f1 = bf2f(f >> 16);
    se0 += e0; se1 += e1;
    sf0 += f0 * e0; sf1 += f1 * e1;
  }
  float y0 = (se0 != 0.f) ? sf0 / se0 : 0.f;
  float y1 = (se1 != 0.f) ? sf1 / se1 : 0.f;
  uintT pk = ((uintT)f2bf(y1) << 16) | (uintT)f2bf(y0);
  *(uintT*)&ybf[(size_t)g * CC + c0] = pk;
}

// ---------------- K5: gather ----------------
__global__ __launch_bounds__(256) void gather_out(const int* __restrict__ ix,
                                                  const float* __restrict__ z,
                                                  float* __restrict__ out) {
  size_t tid = (size_t)blockIdx.x * 256 + threadIdx.x;  // N*128 threads
  int i = (int)(tid >> 7);
  int c4 = ((int)tid & 127) << 2;
  int g = ix[i];
  f32x4 v = *(const f32x4*)&z[(size_t)g * CC + c4];
  *(f32x4*)&out[(size_t)i * CC + c4] = v;
}

extern "C" void kernel_launch(void* const* d_in, const int* in_sizes, int n_in,
                              void* d_out, int out_size, void* d_ws,
                              size_t ws_size, hipStream_t stream) {
  (void)in_sizes; (void)n_in; (void)out_size; (void)ws_size;
  const float* x = (const float*)d_in[0];
  const int* ix = (const int*)d_in[1];
  const float* Wf = (const float*)d_in[2];
  const float* bf_ = (const float*)d_in[3];
  const float* Wg = (const float*)d_in[4];
  const float* bg = (const float*)d_in[5];
  const float* Wh = (const float*)d_in[6];
  const float* bh = (const float*)d_in[7];

  char* ws = (char*)d_ws;
  size_t off = 0;
  ushortT* xb = (ushortT*)(ws + off); off += (size_t)NN * CC * 2;       // 128 MB
  ushortT* wft = (ushortT*)(ws + off); off += (size_t)CC * CC * 2;
  ushortT* wgt = (ushortT*)(ws + off); off += (size_t)CC * CC * 2;
  ushortT* wht = (ushortT*)(ws + off); off += (size_t)CC * CC * 2;
  ushortT* ybf = (ushortT*)(ws + off); off += (size_t)GG * CC * 2;      // 4 MB
  float* z = (float*)(ws + off); off += (size_t)GG * CC * 4;            // 8 MB
  int* cnt = (int*)(ws + off); off += (size_t)GG * 4;
  int* offs = (int*)(ws + off); off += (size_t)(GG + 64) * 4;
  int* cur = (int*)(ws + off); off += (size_t)GG * 4;
  int* rows = (int*)(ws + off); off += (size_t)NN * 4;

  // fx (bf16) and exp_gx (bf16) live in the two halves of d_out until K5.
  ushortT* fxb = (ushortT*)d_out;
  ushortT* expb = (ushortT*)d_out + (size_t)NN * CC;
  float* out = (float*)d_out;

  convert_x<<<dim3(32768), dim3(256), 0, stream>>>(x, xb);
  transpose_w<<<dim3(16, 16, 3), dim3(32, 8), 0, stream>>>(Wf, Wg, Wh, wft, wgt, wht);
  zero_cnt<<<dim3(16), dim3(256), 0, stream>>>(cnt);
  hist_ix<<<dim3(512), dim3(256), 0, stream>>>(ix, cnt);
  scan_cnt<<<dim3(1), dim3(256), 0, stream>>>(cnt, offs, cur);
  fill_rows<<<dim3(512), dim3(256), 0, stream>>>(ix, cur, rows);
  gemm_bf16<0><<<dim3(8192), dim3(256), 0, stream>>>(xb, wft, wgt, bf_, bg, fxb, expb, nullptr);
  group_reduce<<<dim3(GG), dim3(256), 0, stream>>>(expb, fxb, offs, rows, ybf);
  gemm_bf16<1><<<dim3(4, 32), dim3(256), 0, stream>>>(ybf, wht, nullptr, bh, nullptr, nullptr, nullptr, z);
  gather_out<<<dim3(65536), dim3(256), 0, stream>>>(ix, z, out);
}